// Round 5
// baseline (100897.339 us; speedup 1.0000x reference)
//
#include <hip/hip_runtime.h>

#define HH 128      // hidden size
#define G4 512      // 4*HH gates
#define TT 102400   // sequence length
#define BB 8        // batch
#define XS 801      // x_lds per-batch stride (pad: 801%32=1 -> bank spread)
#define HS2 144     // hh2 per-batch stride in halfs (72 dwords -> <=2-way banks)

typedef _Float16 v2h __attribute__((ext_vector_type(2)));
typedef _Float16 v8h __attribute__((ext_vector_type(8)));
typedef float    f4v __attribute__((ext_vector_type(4)));

#define MFMA16(A, B, C) __builtin_amdgcn_mfma_f32_16x16x32_f16((A), (B), (C), 0, 0, 0)

#if __has_builtin(__builtin_amdgcn_fdot2)
#define FDOT2(a, b, c) __builtin_amdgcn_fdot2((a), (b), (c), false)
#else
static __device__ __forceinline__ float fdot2_fb(v2h a, v2h b, float c) {
    return fmaf((float)a[0], (float)b[0], fmaf((float)a[1], (float)b[1], c));
}
#define FDOT2(a, b, c) fdot2_fb((a), (b), (c))
#endif

template<int CTRL>
__device__ __forceinline__ float dpp_mov(float v) {
    return __int_as_float(
        __builtin_amdgcn_update_dpp(0, __float_as_int(v), CTRL, 0xF, 0xF, true));
}

__device__ __forceinline__ float tanh_f(float x) {
    return fmaf(2.0f, __builtin_amdgcn_rcpf(1.0f + __expf(-2.0f * x)), -1.0f);
}
__device__ __forceinline__ float sigm_f(float x) {
    return __builtin_amdgcn_rcpf(1.0f + __expf(-x));
}

union HI { int i; v2h h; };

// R7-verified reduce-to-distinct dot (stage B only).
__device__ __forceinline__ float dotred(const v2h w[8][8],
                                        const _Float16* __restrict__ hsl,
                                        bool bp1, bool bp2, bool bp3) {
    const int4* hp4 = (const int4*)hsl;
    int4 ha = hp4[0], hb = hp4[1];
    int hp[8] = {ha.x, ha.y, ha.z, ha.w, hb.x, hb.y, hb.z, hb.w};
    float acc[8];
#pragma unroll
    for (int r = 0; r < 8; ++r) acc[r] = 0.f;
#pragma unroll
    for (int i = 0; i < 8; ++i) {
        HI u; u.i = hp[i];
#pragma unroll
        for (int r = 0; r < 8; ++r) acc[r] = FDOT2(w[r][i], u.h, acc[r]);
    }
    float b0[4];
#pragma unroll
    for (int m = 0; m < 4; ++m) {
        float send = bp1 ? acc[2 * m] : acc[2 * m + 1];
        float keep = bp1 ? acc[2 * m + 1] : acc[2 * m];
        b0[m] = keep + dpp_mov<0xB1>(send);
    }
    float d0[2];
#pragma unroll
    for (int i = 0; i < 2; ++i) {
        float send = bp2 ? b0[i] : b0[i + 2];
        float keep = bp2 ? b0[i + 2] : b0[i];
        d0[i] = keep + dpp_mov<0x4E>(send);
    }
    float send = bp3 ? d0[0] : d0[1];
    float keep = bp3 ? d0[1] : d0[0];
    return keep + dpp_mov<0x141>(send);
}

// stage-B weight slices, now with half-cell offset (256-thread blocks)
__device__ __forceinline__ void load_w8h(const float* __restrict__ W,
                                         int Q, int j, int ch, v2h w[8][8]) {
#pragma unroll
    for (int r = 0; r < 8; ++r) {
        int row = 64 * ch + 2 * Q + (r & 1) + 128 * (r >> 1);
        const float4* rp = (const float4*)(W + (size_t)row * HH + 16 * j);
#pragma unroll
        for (int i = 0; i < 4; ++i) {
            float4 f = rp[i];
            w[r][2 * i]     = (v2h){(_Float16)f.x, (_Float16)f.y};
            w[r][2 * i + 1] = (v2h){(_Float16)f.z, (_Float16)f.w};
        }
    }
}

// ---------------------------------------------------------------------------
// R15: batch-parallel MFMA chains. R14 post-mortem: step was MFMA-pipe-bound
// per SIMD (32 MFMA/SIMD x ~19cy = 620cy; broadcast cols wasted 15/16 lanes).
// Now: block 0 = layer0, block 1 = layer1; 4 waves (1/SIMD); MFMA cols carry
// the 8 batches (cols 8-15 mirror 0-7). 128 MFMAs/step advance ALL 8 batches.
// Lane (w, lhi, lr): batch bb=lr&7, half hs=lr>>3, cells ccb=32w+16hs+4lhi+r
// (r=0..3). Gates of its cells land in its own D regs (D row=4*lhi+reg,
// col=lr: m89/R14-verified); c stays in registers; h exchanged via padded
// LDS (HS2=144 halfs/batch: <=2-way banks = free). x staged in LDS per chunk;
// xp prefetched 1 step ahead. One __syncthreads per step.
// ---------------------------------------------------------------------------
__global__ void __launch_bounds__(256, 1)
lstm_slot_kernel(
    const float* __restrict__ x,
    const float* __restrict__ Wih0, const float* __restrict__ Whh0,
    const float* __restrict__ bih0, const float* __restrict__ bhh0,
    const float* __restrict__ Wih1, const float* __restrict__ Whh1,
    const float* __restrict__ bih1, const float* __restrict__ bhh1,
    float* __restrict__ h1s, float* __restrict__ c1s,
    float* __restrict__ h2s, float* __restrict__ c2s,
    double* __restrict__ pooled,
    _Float16* __restrict__ h1ring,  // [2][B][chunkT][HH]   fp16
    float* __restrict__ xpring,     // [2][B][chunkT][HH][4] (t,cell,gate) fp32
    int c, int chunkT, int nchunks)
{
    __shared__ __align__(16) _Float16 hh2[2][BB * HS2];
    __shared__ __align__(16) float x_lds[BB * XS];
    const int t = threadIdx.x;

    if (blockIdx.x < 2) {
        // =============== chain blocks (0: layer0, 1: layer1) ===============
        const bool isA = (blockIdx.x == 0);
        const int cc = isA ? c : (c - 2);
        if (cc < 0 || cc >= nchunks) return;

        const int l   = t & 63;
        const int w   = t >> 6;          // wave 0..3 (one per SIMD)
        const int lr  = l & 15;          // A-row-in-tile == D col
        const int lhi = l >> 4;          // k-group / D row-block
        const int bb  = lr & 7;          // batch
        const int hs  = lr >> 3;         // which 16-cell half this lane acts on
        const int ccb = 32 * w + 16 * hs + 4 * lhi;  // first of lane's 4 cells

        // ---- A fragments af[g][h2][kt]: W row = 32w+16*h2+lr+128g,
        //      k = 32*kt + 8*lhi + j (R14-verified maps) ----
        const float* Wc = isA ? Whh0 : Whh1;
        v8h af[4][2][4];
#pragma unroll
        for (int g = 0; g < 4; ++g)
#pragma unroll
            for (int h2 = 0; h2 < 2; ++h2)
#pragma unroll
                for (int kt = 0; kt < 4; ++kt) {
                    const float* wr = Wc + (size_t)(32 * w + 16 * h2 + lr + 128 * g) * HH
                                    + 32 * kt + 8 * lhi;
                    f4v fa = *(const f4v*)wr, fb = *(const f4v*)(wr + 4);
                    v8h v;
                    v[0] = (_Float16)fa[0]; v[1] = (_Float16)fa[1];
                    v[2] = (_Float16)fa[2]; v[3] = (_Float16)fa[3];
                    v[4] = (_Float16)fb[0]; v[5] = (_Float16)fb[1];
                    v[6] = (_Float16)fb[2]; v[7] = (_Float16)fb[3];
                    af[g][h2][kt] = v;
                }

        // bias folded into MFMA C-in (layer0; layer1 bias lives in xp)
        f4v cin[4][2];
#pragma unroll
        for (int g = 0; g < 4; ++g)
#pragma unroll
            for (int h2 = 0; h2 < 2; ++h2) cin[g][h2] = (f4v){0.f, 0.f, 0.f, 0.f};
        float wih[4][4];
#pragma unroll
        for (int r = 0; r < 4; ++r)
#pragma unroll
            for (int g = 0; g < 4; ++g) wih[r][g] = 0.f;
        if (isA) {
#pragma unroll
            for (int g = 0; g < 4; ++g)
#pragma unroll
                for (int h2 = 0; h2 < 2; ++h2)
#pragma unroll
                    for (int r = 0; r < 4; ++r) {
                        int row = 32 * w + 16 * h2 + 4 * lhi + r + 128 * g;
                        cin[g][h2][r] = bih0[row] + bhh0[row];
                    }
#pragma unroll
            for (int r = 0; r < 4; ++r)
#pragma unroll
                for (int g = 0; g < 4; ++g) wih[r][g] = Wih0[ccb + r + 128 * g];
        }

        float* hst = isA ? h1s : h2s;
        float* cst = isA ? c1s : c2s;
        float cr0 = cst[bb * HH + ccb + 0];
        float cr1 = cst[bb * HH + ccb + 1];
        float cr2 = cst[bb * HH + ccb + 2];
        float cr3 = cst[bb * HH + ccb + 3];
        float hl0 = 0.f, hl1 = 0.f, hl2 = 0.f, hl3 = 0.f;
        float pac0 = 0.f, pac1 = 0.f, pac2 = 0.f, pac3 = 0.f;

        // stage h into hh2[0] (step 0 reads buf 0)
        for (int i = t; i < BB * HH; i += 256)
            hh2[0][(i >> 7) * HS2 + (i & 127)] = (_Float16)hst[i];
        // stage this chunk's x into LDS (layer0)
        if (isA) {
            for (int b_ = 0; b_ < 8; ++b_)
                for (int tp = t; tp < chunkT; tp += 256)
                    x_lds[b_ * XS + tp] = x[(size_t)b_ * TT + (size_t)cc * chunkT + tp];
        }

        _Float16* rp = h1ring + ((size_t)((c & 1) * BB + bb)) * (size_t)chunkT * HH + ccb;
        const float* xps = xpring
            + ((size_t)((cc & 1) * BB + bb)) * (size_t)chunkT * G4 + 4 * ccb;

        f4v xc0 = {0,0,0,0}, xc1 = {0,0,0,0}, xc2 = {0,0,0,0}, xc3 = {0,0,0,0};
        f4v xn0 = {0,0,0,0}, xn1 = {0,0,0,0}, xn2 = {0,0,0,0}, xn3 = {0,0,0,0};
        if (!isA) {
            xc0 = *(const f4v*)(xps);     xc1 = *(const f4v*)(xps + 4);
            xc2 = *(const f4v*)(xps + 8); xc3 = *(const f4v*)(xps + 12);
        }
        __syncthreads();

#define CSTEP(PB, S, SN, XC0,XC1,XC2,XC3, XN0,XN1,XN2,XN3) do {               \
        if (!isA && (SN) < chunkT) {                                          \
            const float* q_ = xps + (size_t)(SN) * G4;                        \
            XN0 = *(const f4v*)q_;        XN1 = *(const f4v*)(q_ + 4);        \
            XN2 = *(const f4v*)(q_ + 8);  XN3 = *(const f4v*)(q_ + 12);       \
        }                                                                     \
        const _Float16* hb_ = &hh2[PB][bb * HS2 + 8 * lhi];                   \
        v8h B0_ = *(const v8h*)(hb_);                                         \
        v8h B1_ = *(const v8h*)(hb_ + 32);                                    \
        v8h B2_ = *(const v8h*)(hb_ + 64);                                    \
        v8h B3_ = *(const v8h*)(hb_ + 96);                                    \
        f4v a00_ = cin[0][0], a01_ = cin[0][1], a10_ = cin[1][0],             \
            a11_ = cin[1][1], a20_ = cin[2][0], a21_ = cin[2][1],             \
            a30_ = cin[3][0], a31_ = cin[3][1];                               \
        a00_ = MFMA16(af[0][0][0], B0_, a00_);                                \
        a00_ = MFMA16(af[0][0][1], B1_, a00_);                                \
        a00_ = MFMA16(af[0][0][2], B2_, a00_);                                \
        a00_ = MFMA16(af[0][0][3], B3_, a00_);                                \
        a10_ = MFMA16(af[1][0][0], B0_, a10_);                                \
        a10_ = MFMA16(af[1][0][1], B1_, a10_);                                \
        a10_ = MFMA16(af[1][0][2], B2_, a10_);                                \
        a10_ = MFMA16(af[1][0][3], B3_, a10_);                                \
        a20_ = MFMA16(af[2][0][0], B0_, a20_);                                \
        a20_ = MFMA16(af[2][0][1], B1_, a20_);                                \
        a20_ = MFMA16(af[2][0][2], B2_, a20_);                                \
        a20_ = MFMA16(af[2][0][3], B3_, a20_);                                \
        a30_ = MFMA16(af[3][0][0], B0_, a30_);                                \
        a30_ = MFMA16(af[3][0][1], B1_, a30_);                                \
        a30_ = MFMA16(af[3][0][2], B2_, a30_);                                \
        a30_ = MFMA16(af[3][0][3], B3_, a30_);                                \
        a01_ = MFMA16(af[0][1][0], B0_, a01_);                                \
        a01_ = MFMA16(af[0][1][1], B1_, a01_);                                \
        a01_ = MFMA16(af[0][1][2], B2_, a01_);                                \
        a01_ = MFMA16(af[0][1][3], B3_, a01_);                                \
        a11_ = MFMA16(af[1][1][0], B0_, a11_);                                \
        a11_ = MFMA16(af[1][1][1], B1_, a11_);                                \
        a11_ = MFMA16(af[1][1][2], B2_, a11_);                                \
        a11_ = MFMA16(af[1][1][3], B3_, a11_);                                \
        a21_ = MFMA16(af[2][1][0], B0_, a21_);                                \
        a21_ = MFMA16(af[2][1][1], B1_, a21_);                                \
        a21_ = MFMA16(af[2][1][2], B2_, a21_);                                \
        a21_ = MFMA16(af[2][1][3], B3_, a21_);                                \
        a31_ = MFMA16(af[3][1][0], B0_, a31_);                                \
        a31_ = MFMA16(af[3][1][1], B1_, a31_);                                \
        a31_ = MFMA16(af[3][1][2], B2_, a31_);                                \
        a31_ = MFMA16(af[3][1][3], B3_, a31_);                                \
        f4v vi_ = hs ? a01_ : a00_;  f4v vf_ = hs ? a11_ : a10_;              \
        f4v vg_ = hs ? a21_ : a20_;  f4v vo_ = hs ? a31_ : a30_;              \
        float xt_ = x_lds[bb * XS + (S)];                                     \
        float h0_, h1_, h2v_, h3_;                                            \
        {                                                                     \
            float pi_, pf_, pg_, po_;                                         \
            if (isA) { pi_ = fmaf(xt_, wih[0][0], vi_[0]);                    \
                       pf_ = fmaf(xt_, wih[0][1], vf_[0]);                    \
                       pg_ = fmaf(xt_, wih[0][2], vg_[0]);                    \
                       po_ = fmaf(xt_, wih[0][3], vo_[0]); }                  \
            else { pi_ = vi_[0] + XC0[0]; pf_ = vf_[0] + XC0[1];              \
                   pg_ = vg_[0] + XC0[2]; po_ = vo_[0] + XC0[3]; }            \
            float gi_ = sigm_f(pi_), gf_ = sigm_f(pf_);                       \
            float gg_ = tanh_f(pg_), go_ = sigm_f(po_);                       \
            cr0 = fmaf(gf_, cr0, gi_ * gg_);  h0_ = go_ * tanh_f(cr0);        \
        }                                                                     \
        {                                                                     \
            float pi_, pf_, pg_, po_;                                         \
            if (isA) { pi_ = fmaf(xt_, wih[1][0], vi_[1]);                    \
                       pf_ = fmaf(xt_, wih[1][1], vf_[1]);                    \
                       pg_ = fmaf(xt_, wih[1][2], vg_[1]);                    \
                       po_ = fmaf(xt_, wih[1][3], vo_[1]); }                  \
            else { pi_ = vi_[1] + XC1[0]; pf_ = vf_[1] + XC1[1];              \
                   pg_ = vg_[1] + XC1[2]; po_ = vo_[1] + XC1[3]; }            \
            float gi_ = sigm_f(pi_), gf_ = sigm_f(pf_);                       \
            float gg_ = tanh_f(pg_), go_ = sigm_f(po_);                       \
            cr1 = fmaf(gf_, cr1, gi_ * gg_);  h1_ = go_ * tanh_f(cr1);        \
        }                                                                     \
        {                                                                     \
            float pi_, pf_, pg_, po_;                                         \
            if (isA) { pi_ = fmaf(xt_, wih[2][0], vi_[2]);                    \
                       pf_ = fmaf(xt_, wih[2][1], vf_[2]);                    \
                       pg_ = fmaf(xt_, wih[2][2], vg_[2]);                    \
                       po_ = fmaf(xt_, wih[2][3], vo_[2]); }                  \
            else { pi_ = vi_[2] + XC2[0]; pf_ = vf_[2] + XC2[1];              \
                   pg_ = vg_[2] + XC2[2]; po_ = vo_[2] + XC2[3]; }            \
            float gi_ = sigm_f(pi_), gf_ = sigm_f(pf_);                       \
            float gg_ = tanh_f(pg_), go_ = sigm_f(po_);                       \
            cr2 = fmaf(gf_, cr2, gi_ * gg_);  h2v_ = go_ * tanh_f(cr2);       \
        }                                                                     \
        {                                                                     \
            float pi_, pf_, pg_, po_;                                         \
            if (isA) { pi_ = fmaf(xt_, wih[3][0], vi_[3]);                    \
                       pf_ = fmaf(xt_, wih[3][1], vf_[3]);                    \
                       pg_ = fmaf(xt_, wih[3][2], vg_[3]);                    \
                       po_ = fmaf(xt_, wih[3][3], vo_[3]); }                  \
            else { pi_ = vi_[3] + XC3[0]; pf_ = vf_[3] + XC3[1];              \
                   pg_ = vg_[3] + XC3[2]; po_ = vo_[3] + XC3[3]; }            \
            float gi_ = sigm_f(pi_), gf_ = sigm_f(pf_);                       \
            float gg_ = tanh_f(pg_), go_ = sigm_f(po_);                       \
            cr3 = fmaf(gf_, cr3, gi_ * gg_);  h3_ = go_ * tanh_f(cr3);        \
        }                                                                     \
        union { v2h hp[2]; unsigned long long u; } pk_;                       \
        pk_.hp[0] = (v2h){(_Float16)h0_, (_Float16)h1_};                      \
        pk_.hp[1] = (v2h){(_Float16)h2v_, (_Float16)h3_};                     \
        *(unsigned long long*)(&hh2[(PB) ^ 1][bb * HS2 + ccb]) = pk_.u;       \
        if (isA) *(unsigned long long*)(rp + (size_t)(S) * HH) = pk_.u;       \
        else { pac0 += h0_; pac1 += h1_; pac2 += h2v_; pac3 += h3_; }         \
        hl0 = h0_; hl1 = h1_; hl2 = h2v_; hl3 = h3_;                          \
        __syncthreads();                                                      \
    } while (0)

        for (int s = 0; s < chunkT; s += 2) {
            CSTEP(0, s,     s + 1, xc0, xc1, xc2, xc3, xn0, xn1, xn2, xn3);
            CSTEP(1, s + 1, s + 2, xn0, xn1, xn2, xn3, xc0, xc1, xc2, xc3);
        }
#undef CSTEP

        cst[bb * HH + ccb + 0] = cr0; cst[bb * HH + ccb + 1] = cr1;
        cst[bb * HH + ccb + 2] = cr2; cst[bb * HH + ccb + 3] = cr3;
        hst[bb * HH + ccb + 0] = hl0; hst[bb * HH + ccb + 1] = hl1;
        hst[bb * HH + ccb + 2] = hl2; hst[bb * HH + ccb + 3] = hl3;
        if (!isA) {
            pooled[bb * HH + ccb + 0] += (double)pac0;
            pooled[bb * HH + ccb + 1] += (double)pac1;
            pooled[bb * HH + ccb + 2] += (double)pac2;
            pooled[bb * HH + ccb + 3] += (double)pac3;
        }

    } else {
        // ------- stage B: xp1 = Wih1 @ h1 + bias, chunk c-1 (256 thr) ------
        const int bc = c - 1;
        if (bc < 0 || bc >= nchunks) return;
        const int ib = blockIdx.x - 2;        // 0..127
        const int bb2 = ib >> 4;              // batch
        const int sl = (ib >> 1) & 7;         // t-slice
        const int ch = ib & 1;                // cell-half [0,64) or [64,128)
        const int Q = t >> 3;                 // 0..31
        const int j = t & 7;
        const bool bp1 = ((j ^ (j >> 2)) & 1) != 0;
        const bool bp2 = ((j ^ (j >> 1)) & 1) != 0;
        const bool bp3 = ((j >> 2) & 1) != 0;
        const int cellj = bp1 ? 1 : 0;
        const int gatej = (bp2 ? 2 : 0) + (bp3 ? 1 : 0);
        const int myc   = 64 * ch + 2 * Q + cellj;
        const int myrow = myc + 128 * gatej;

        v2h wB[8][8];
        load_w8h(Wih1, Q, j, ch, wB);
        const float bias_l = bih1[myrow] + bhh1[myrow];
        const _Float16* hrp = h1ring
            + ((size_t)((bc & 1) * BB + bb2)) * (size_t)chunkT * HH;
        float* xpw = xpring + ((size_t)((bc & 1) * BB + bb2)) * (size_t)chunkT * G4;
        _Float16* hhB = &hh2[0][0];           // 2*HH halfs, reuses chain LDS
        if (t < HH) hhB[t] = hrp[(size_t)sl * HH + t];
        __syncthreads();
        int pb = 0;
        for (int tt = sl; tt < chunkT; tt += 8) {
            int ttn = tt + 8;
            bool pf = (t < HH) && (ttn < chunkT);
            _Float16 hn = (_Float16)0.f;
            if (pf) hn = hrp[(size_t)ttn * HH + t];
            float sfin = dotred(wB, hhB + pb * HH + 16 * j, bp1, bp2, bp3);
            if (pf) hhB[(pb ^ 1) * HH + t] = hn;
            xpw[(size_t)tt * G4 + 4 * myc + gatej] = sfin + bias_l;
            __syncthreads();
            pb ^= 1;
        }
    }
}

// ---------------- head: mean-pool (done) -> FC+ReLU -> FC ------------------
__global__ void head_kernel(const double* __restrict__ pooled,
                            const float* __restrict__ fcW1, const float* __restrict__ fcb1,
                            const float* __restrict__ fcW2, const float* __restrict__ fcb2,
                            float* __restrict__ out)
{
    __shared__ float p_s[HH];
    __shared__ float hid_s[64];
    const int b = blockIdx.x, t = threadIdx.x;
    if (t < HH) p_s[t] = (float)(pooled[b * HH + t] * (1.0 / (double)TT));
    __syncthreads();
    if (t < 64) {
        float acc = fcb1[t];
#pragma unroll 8
        for (int k = 0; k < HH; ++k) acc = fmaf(p_s[k], fcW1[t * HH + k], acc);
        hid_s[t] = fmaxf(acc, 0.f);
    }
    __syncthreads();
    if (t < 11) {
        float acc = fcb2[t];
#pragma unroll
        for (int k = 0; k < 64; ++k) acc = fmaf(hid_s[k], fcW2[t * 64 + k], acc);
        out[b * 11 + t] = acc;
    }
}

// ---------------------------------------------------------------------------
extern "C" void kernel_launch(void* const* d_in, const int* in_sizes, int n_in,
                              void* d_out, int out_size, void* d_ws, size_t ws_size,
                              hipStream_t stream)
{
    const float* x    = (const float*)d_in[0];
    const float* Wih0 = (const float*)d_in[1];
    const float* Whh0 = (const float*)d_in[2];
    const float* bih0 = (const float*)d_in[3];
    const float* bhh0 = (const float*)d_in[4];
    const float* Wih1 = (const float*)d_in[5];
    const float* Whh1 = (const float*)d_in[6];
    const float* bih1 = (const float*)d_in[7];
    const float* bhh1 = (const float*)d_in[8];
    const float* fcW1 = (const float*)d_in[9];
    const float* fcb1 = (const float*)d_in[10];
    const float* fcW2 = (const float*)d_in[11];
    const float* fcb2 = (const float*)d_in[12];
    float* out = (float*)d_out;

    // ---- workspace layout ----
    char* wsp = (char*)d_ws;
    float*  h1s    = (float*) (wsp + 0);
    float*  c1s    = (float*) (wsp + 4096);
    float*  h2s    = (float*) (wsp + 8192);
    float*  c2s    = (float*) (wsp + 12288);
    double* pooled = (double*)(wsp + 16384);          // 8 KB
    const size_t STATE_BYTES = 24576;

    // per-t ring bytes: h1 fp16 4096 + xp fp32 32768 = 36864
    static const int cands[] = {800, 400, 160, 80, 40, 8};
    int chunkT = 8;
    for (int i = 0; i < 6; ++i) {
        size_t need = STATE_BYTES + (size_t)36864 * (size_t)cands[i];
        if (need <= ws_size) { chunkT = cands[i]; break; }
    }
    const int nchunks = TT / chunkT;

    _Float16* h1ring = (_Float16*)(wsp + STATE_BYTES);
    float* xpring = (float*)(wsp + STATE_BYTES + (size_t)2 * BB * chunkT * HH * 2);

    // zero persistent state (h/c/pooled); ws is re-poisoned before every call
    hipMemsetAsync(d_ws, 0, STATE_BYTES, stream);

    // pipeline: slot c runs A(c) || B(c-1) || C(c-2)
    const int nslots = nchunks + 2;
    for (int c = 0; c < nslots; ++c) {
        lstm_slot_kernel<<<130, 256, 0, stream>>>(
            x, Wih0, Whh0, bih0, bhh0, Wih1, Whh1, bih1, bhh1,
            h1s, c1s, h2s, c2s, pooled, h1ring, xpring,
            c, chunkT, nchunks);
    }
    head_kernel<<<BB, 128, 0, stream>>>(pooled, fcW1, fcb1, fcW2, fcb2, out);
}